// Round 9
// baseline (126.801 us; speedup 1.0000x reference)
//
#include <hip/hip_runtime.h>

// ReconstructPatchImage: out[b,c,y,x] = sum of 8 permuted gathers of [B,HW,C] inputs.
// B=64, HW=196 (H=W=14), C=1024, float32.
//
// Per-input flat (per-batch) source index for output (c, q=y*14+x):
//   in0: q*1024+c   in1: (195-q)*1024+c
//   in2: x*14336 + c*14 + y                      (channel-mixing col-major)
//   in3: (195 - x*14 - hi)*1024 + lo, t=c*14+y   (reversed col-major)
//   in4: p5f(y,x)   in5: p6f(y,x)   in6: p5f(y,13-x)   in7: p5f(13-y,x)
//
// R8 = R7 with the LDS-pointer-array compile error fixed (compute buffer
// addresses inline; no addrspace-cast array initializer):
//  - c-tile 32: slab 24.5KB, 3 buffers = 73.5KB -> 2 resident blocks/CU
//  - 2 batches per block, 16 slabs through ONE never-draining counted-vmcnt
//    pipeline (both acc sets in registers; FIFO stays loads-only)
//  - grid 1024 -> 2 sequential rounds/CU, cross-overlapped by co-resident block
//  - per-block input-order rotation (decorrelates read streams)
//  - epilogue: XOR-swizzled LDS transpose + dense-dword nontemporal stores

#define N_C   1024
#define BSTR  (196 * 1024)
#define SLABF 6272            // floats per 196x32 slab

__device__ __forceinline__ int p5f(int y, int x) {   // diag TL->BR rank
    int s = x + y;
    int st = (s <= 13) ? ((s * (s + 1)) >> 1) : (105 + (((41 - s) * (s - 14)) >> 1));
    return st + y - ((s > 13) ? (s - 13) : 0);
}
__device__ __forceinline__ int p6f(int y, int x) {   // reversed-diag rank
    int s = x + y;
    int st = (s <= 13) ? ((s * (s + 1)) >> 1) : (105 + (((41 - s) * (s - 14)) >> 1));
    int x1 = (s < 13) ? s : 13;
    return 195 - st - (x1 - x);
}

__device__ __forceinline__ void gll16(const float* g, float* l) {
    __builtin_amdgcn_global_load_lds(
        (const __attribute__((address_space(1))) unsigned int*)g,
        (__attribute__((address_space(3))) unsigned int*)l, 16, 0, 0);
}
__device__ __forceinline__ void gll4(const float* g, float* l) {
    __builtin_amdgcn_global_load_lds(
        (const __attribute__((address_space(1))) unsigned int*)g,
        (__attribute__((address_space(3))) unsigned int*)l, 4, 0, 0);
}

#define BAR()   __builtin_amdgcn_s_barrier()
#define VMW(n)  asm volatile("s_waitcnt vmcnt(" #n ")" ::: "memory")
#define LGKM0   asm volatile("s_waitcnt lgkmcnt(0)" ::: "memory")

__global__ __launch_bounds__(448) void recon_kernel(
    const float* __restrict__ in0, const float* __restrict__ in1,
    const float* __restrict__ in2, const float* __restrict__ in3,
    const float* __restrict__ in4, const float* __restrict__ in5,
    const float* __restrict__ in6, const float* __restrict__ in7,
    float* __restrict__ out)
{
    __shared__ __align__(16) float lds[3 * SLABF];   // 75,264 B -> 2 blocks/CU
    const int tid  = threadIdx.x;
    const int lane = tid & 63;
    const int chl  = lane & 31;                              // channel within tile
    const int qh   = lane >> 5;                              // q parity half
    const int w0   = __builtin_amdgcn_readfirstlane(tid >> 6);  // 0..6
    const int c0   = blockIdx.x * 32;                        // channel tile base
    const int b0   = blockIdx.y * 2;                         // batch pair
    const int rot  = (blockIdx.x + 3 * blockIdx.y) & 7;

    const float* ins[8] = { in0, in1, in2, in3, in4, in5, in6, in7 };

    // ---- staging: slab = 24 x w16 (waves 0-5, 4 each) + 2 x w4 (wave 6) ----
    auto stage_any = [&](int ii, int b, float* sb) {
        const float* gb = ins[ii] + (size_t)b * BSTR;
        if (ii == 2) {                        // col-major forward
            if (w0 < 6) {
                #pragma unroll
                for (int jj = 0; jj < 4; ++jj) {
                    int J  = w0 * 4 + jj;
                    int gi = J * 64 + lane;
                    int x  = gi / 112;
                    int r4 = (gi - x * 112) * 4;
                    gll16(gb + x * 14336 + c0 * 14 + r4, sb + J * 256);
                }
            } else {
                #pragma unroll
                for (int i2 = 0; i2 < 2; ++i2) {
                    int fi = 6144 + i2 * 64 + lane;
                    int r  = fi - 5824;                      // remainder is all x=13
                    gll4(gb + 13 * 14336 + c0 * 14 + r, sb + 6144 + i2 * 64);
                }
            }
        } else if (ii == 3) {                 // col-major reversed
            if (w0 < 6) {
                #pragma unroll
                for (int jj = 0; jj < 4; ++jj) {
                    int J  = w0 * 4 + jj;
                    int gi = J * 64 + lane;
                    int x  = gi / 112;
                    int r4 = (gi - x * 112) * 4;
                    int t  = c0 * 14 + r4;                   // never straddles %1024
                    int hi = t >> 10, lo = t & 1023;
                    int p  = 195 - x * 14 - hi;
                    gll16(gb + p * N_C + lo, sb + J * 256);
                }
            } else {
                #pragma unroll
                for (int i2 = 0; i2 < 2; ++i2) {
                    int fi = 6144 + i2 * 64 + lane;
                    int r  = fi - 5824;
                    int t  = c0 * 14 + r;
                    int hi = t >> 10, lo = t & 1023;
                    int p  = 13 - hi;                        // 195 - 13*14 - hi
                    gll4(gb + p * N_C + lo, sb + 6144 + i2 * 64);
                }
            }
        } else {                              // row-layout inputs staged linearly
            if (w0 < 6) {
                #pragma unroll
                for (int jj = 0; jj < 4; ++jj) {
                    int J   = w0 * 4 + jj;
                    int gi  = J * 64 + lane;
                    int row = gi >> 3;
                    int co  = (gi & 7) * 4;
                    gll16(gb + row * N_C + c0 + co, sb + J * 256);
                }
            } else {
                #pragma unroll
                for (int i2 = 0; i2 < 2; ++i2) {
                    int fi  = 6144 + i2 * 64 + lane;
                    int row = fi >> 5;
                    int ch  = fi & 31;
                    gll4(gb + row * N_C + c0 + ch, sb + 6144 + i2 * 64);
                }
            }
        }
    };

    // ---- prologue: first 3 slabs in flight, VALU precompute under latency ----
    stage_any((0 + rot) & 7, b0, lds);
    stage_any((1 + rot) & 7, b0, lds + SLABF);
    stage_any((2 + rot) & 7, b0, lds + 2 * SLABF);

    unsigned pp45[14], pp67[14];
    int cmoff[14];
    #pragma unroll
    for (int k = 0; k < 14; ++k) {
        int q = 28 * w0 + 2 * k + qh;
        int y = q / 14;
        int x = q - 14 * y;
        pp45[k] = (unsigned)p5f(y, x) | ((unsigned)p6f(y, x) << 16);
        pp67[k] = (unsigned)p5f(y, 13 - x) | ((unsigned)p5f(13 - y, x) << 16);
        cmoff[k] = x * 448 + chl * 14 + y;
    }

    float a0[14], a1[14];
    #pragma unroll
    for (int k = 0; k < 14; ++k) { a0[k] = 0.f; a1[k] = 0.f; }

    auto acc_any = [&](int ii, const float* sb, float (&A)[14]) {
        if (ii == 2 || ii == 3) {
            #pragma unroll
            for (int k = 0; k < 14; ++k) A[k] += sb[cmoff[k]];
        } else {
            #pragma unroll
            for (int k = 0; k < 14; ++k) {
                int p;
                int q = 28 * w0 + 2 * k + qh;
                if      (ii == 0) p = q;
                else if (ii == 1) p = 195 - q;
                else if (ii == 4) p = (int)(pp45[k] & 0xffffu);
                else if (ii == 5) p = (int)(pp45[k] >> 16);
                else if (ii == 6) p = (int)(pp67[k] & 0xffffu);
                else              p = (int)(pp67[k] >> 16);
                A[k] += sb[p * 32 + chl];
            }
        }
    };

    // per-wave depth waits: waves 0-5 = 4 loads/slab, wave 6 = 2
    #define VMW_D2  do { if (w0 < 6) { VMW(8); } else { VMW(4); } } while (0)
    #define VMW_D1  do { if (w0 < 6) { VMW(4); } else { VMW(2); } } while (0)

    // ---- 16 phases (2 batches x 8 inputs), pipeline never drains mid-loop ----
    #pragma unroll 1
    for (int s = 0; s < 16; ++s) {
        if (s < 14)       { VMW_D2; }
        else if (s == 14) { VMW_D1; }
        else              { VMW(0); }
        BAR();
        float* sb = lds + (s % 3) * SLABF;
        int ii = (s + rot) & 7;
        if (s < 8) acc_any(ii, sb, a0);
        else       acc_any(ii, sb, a1);
        LGKM0; BAR();
        if (s + 3 < 16) {
            int s2 = s + 3;
            stage_any((s2 + rot) & 7, b0 + (s2 >> 3), sb);
        }
    }
    #undef VMW_D2
    #undef VMW_D1

    // ---- epilogue: XOR-swizzled transpose (one slab buffer each) + NT stores ----
    __syncthreads();                       // all pipeline reads done
    #pragma unroll
    for (int k = 0; k < 14; ++k) {
        int q = 28 * w0 + 2 * k + qh;
        lds[q * 32 + (chl ^ (q & 31))] = a0[k];
        lds[SLABF + q * 32 + (chl ^ (q & 31))] = a1[k];
    }
    __syncthreads();
    {
        float* ob0 = out + (size_t)b0 * BSTR + (size_t)c0 * 196;
        float* ob1 = ob0 + BSTR;
        #pragma unroll
        for (int k = 0; k < 14; ++k) {
            int i  = tid + k * 448;        // 0..6271, dense dwords per wave
            int cg = i / 196;
            int q  = i - cg * 196;
            int sw = q * 32 + (cg ^ (q & 31));
            __builtin_nontemporal_store(lds[sw], ob0 + cg * 196 + q);
            __builtin_nontemporal_store(lds[SLABF + sw], ob1 + cg * 196 + q);
        }
    }
}

extern "C" void kernel_launch(void* const* d_in, const int* in_sizes, int n_in,
                              void* d_out, int out_size, void* d_ws, size_t ws_size,
                              hipStream_t stream) {
    dim3 grid(32, 32);   // x: channel tile (1024/32), y: batch pair (64/2)
    dim3 block(448);     // 7 waves; wave w owns q = 28w..28w+27 (2 q per lane-half)
    recon_kernel<<<grid, block, 0, stream>>>(
        (const float*)d_in[0], (const float*)d_in[1], (const float*)d_in[2],
        (const float*)d_in[3], (const float*)d_in[4], (const float*)d_in[5],
        (const float*)d_in[6], (const float*)d_in[7], (float*)d_out);
}

// Round 10
// 97.247 us; speedup vs baseline: 1.3039x; 1.3039x over previous
//
#include <hip/hip_runtime.h>

// ReconstructPatchImage: out[b,c,y,x] = sum of 8 permuted gathers of [B,HW,C] inputs.
// B=64, HW=196 (H=W=14), C=1024, float32.
//
// Per-input flat (per-batch) source index for output (c, q=y*14+x):
//   in0: q*1024+c   in1: (195-q)*1024+c
//   in2: x*14336 + c*14 + y                      (channel-mixing col-major)
//   in3: (195 - x*14 - hi)*1024 + lo, t=c*14+y   (reversed col-major)
//   in4: p5f(y,x)   in5: p6f(y,x)   in6: p5f(y,13-x)   in7: p5f(13-y,x)
//
// R9: convoy-free. Each of 7 waves owns q = 28w..28w+27 and a PRIVATE
// 3-buffer LDS pipeline (3 x 28rows x 64ch) for the 6 row-permuted inputs.
// gll16's per-lane GLOBAL address stages 4 arbitrary permuted rows per
// instruction (16 lanes x 16B each) -> staging traffic exactly clean, acc
// reads linear. Per-wave counted vmcnt, ZERO mid-kernel barriers; the 7
// drifting waves overlap each other's stalls instead of convoying.
// in2/in3: R1's proven-clean float2 register gathers, consumed in prologue.
// Epilogue: R6's proven LDS-transpose + nontemporal coalesced stores.

#define N_C   1024
#define BSTR  (196 * 1024)

__device__ __forceinline__ int p5f(int y, int x) {   // diag TL->BR rank
    int s = x + y;
    int st = (s <= 13) ? ((s * (s + 1)) >> 1) : (105 + (((41 - s) * (s - 14)) >> 1));
    return st + y - ((s > 13) ? (s - 13) : 0);
}
__device__ __forceinline__ int p6f(int y, int x) {   // reversed-diag rank
    int s = x + y;
    int st = (s <= 13) ? ((s * (s + 1)) >> 1) : (105 + (((41 - s) * (s - 14)) >> 1));
    int x1 = (s < 13) ? s : 13;
    return 195 - st - (x1 - x);
}

__device__ __forceinline__ void gll16(const float* g, float* l) {
    __builtin_amdgcn_global_load_lds(
        (const __attribute__((address_space(1))) unsigned int*)g,
        (__attribute__((address_space(3))) unsigned int*)l, 16, 0, 0);
}

#define SB()    __builtin_amdgcn_sched_barrier(0)
#define VMW(n)  asm volatile("s_waitcnt vmcnt(" #n ")" ::: "memory")
#define LGKM0   asm volatile("s_waitcnt lgkmcnt(0)" ::: "memory")

__global__ __launch_bounds__(448) void recon_kernel(
    const float* __restrict__ in0, const float* __restrict__ in1,
    const float* __restrict__ in2, const float* __restrict__ in3,
    const float* __restrict__ in4, const float* __restrict__ in5,
    const float* __restrict__ in6, const float* __restrict__ in7,
    float* __restrict__ out)
{
    __shared__ __align__(16) float lds[7 * 3 * 1792];   // 150,528 B; epilogue aliases
    const int tid  = threadIdx.x;
    const int lane = tid & 63;
    const int w0   = __builtin_amdgcn_readfirstlane(tid >> 6);  // 0..6
    const int c0   = blockIdx.x * 64;
    const int b    = blockIdx.y;
    const size_t boff = (size_t)b * BSTR;
    const int rot  = (blockIdx.x + 3 * blockIdx.y) % 6;

    float* wbuf = lds + w0 * 5376;        // 3 private 1792-float buffers

    // 6 perm inputs, rotated start per block (decorrelate device-wide streams)
    const float* ins6[6] = { in0 + boff, in1 + boff, in4 + boff,
                             in5 + boff, in6 + boff, in7 + boff };

    // ---- stage one private 28x64 slab: 7 gll16, 4 permuted rows each ----
    auto stage_perm = [&](int ii, float* sb) {
        const float* gb = ins6[ii];
        const int rlo = lane >> 4;            // row-within-quad (per-lane!)
        const int ch4 = (lane & 15) << 2;     // float offset within row segment
        #pragma unroll
        for (int j = 0; j < 7; ++j) {
            int q = 28 * w0 + 4 * j + rlo;
            int y = (int)((unsigned)q / 14u);
            int x = q - 14 * y;
            int p;
            switch (ii) {
                case 0:  p = q;                break;
                case 1:  p = 195 - q;          break;
                case 2:  p = p5f(y, x);        break;
                case 3:  p = p6f(y, x);        break;
                case 4:  p = p5f(y, 13 - x);   break;
                default: p = p5f(13 - y, x);   break;
            }
            gll16(gb + p * N_C + c0 + ch4, sb + j * 256);
        }
    };

    float  acc[28];
    float2 f2[28];

    // ---- prologue: issue in2/in3 register gathers, then 3 slabs ----
    {   // in2 forward: per x, float2 covers y = 2w, 2w+1
        const float* p2 = in2 + boff + (c0 + lane) * 14 + 2 * w0;
        #pragma unroll
        for (int x = 0; x < 14; ++x) f2[x] = *(const float2*)(p2 + x * 14336);
    }
    {   // in3 reversed: t even -> pair never straddles the 1024-float boundary
        const float* p3 = in3 + boff;
        int t = (c0 + lane) * 14 + 2 * w0;
        int hi = t >> 10, lo = t & 1023;
        #pragma unroll
        for (int x = 0; x < 14; ++x) {
            int p = 195 - x * 14 - hi;
            f2[14 + x] = *(const float2*)(p3 + p * N_C + lo);
        }
    }
    SB();
    stage_perm((0 + rot) % 6, wbuf);        SB();
    stage_perm((1 + rot) % 6, wbuf + 1792); SB();
    stage_perm((2 + rot) % 6, wbuf + 3584); SB();

    VMW(21); SB();                          // f2 complete; 21 gll16 stay in flight
    #pragma unroll
    for (int x = 0; x < 14; ++x) {
        acc[x]      = f2[x].x + f2[14 + x].x;
        acc[14 + x] = f2[x].y + f2[14 + x].y;
    }
    SB();

    // ---- 6 per-wave phases, no barriers, counted vmcnt ----
    #pragma unroll
    for (int s = 0; s < 6; ++s) {
        if (s < 4)       { VMW(14); }
        else if (s == 4) { VMW(7);  }
        else             { VMW(0);  }
        SB();
        float* sb = wbuf + (s % 3) * 1792;
        #pragma unroll
        for (int k = 0; k < 28; ++k) acc[k] += sb[k * 64 + lane];
        if (s + 3 < 6) {
            LGKM0; SB();
            stage_perm((s + 3 + rot) % 6, sb);
            SB();
        }
    }

    // ---- epilogue: LDS transpose (stride 65) + nontemporal coalesced stores ----
    __syncthreads();                        // all private-buffer reads done
    float* tr = lds;                        // 196*65 = 12740 floats (aliases wbufs)
    #pragma unroll
    for (int k = 0; k < 28; ++k) {
        int q = 28 * w0 + k;
        tr[q * 65 + lane] = acc[k];
    }
    __syncthreads();
    float* ob = out + boff + (size_t)c0 * 196;
    #pragma unroll
    for (int k = 0; k < 28; ++k) {
        int i  = tid + k * 448;             // 0..12543, dense dwords per wave
        int cg = i / 196;
        int q  = i - cg * 196;
        __builtin_nontemporal_store(tr[q * 65 + cg], ob + cg * 196 + q);
    }
}

extern "C" void kernel_launch(void* const* d_in, const int* in_sizes, int n_in,
                              void* d_out, int out_size, void* d_ws, size_t ws_size,
                              hipStream_t stream) {
    dim3 grid(16, 64);   // x: channel tile (1024/64), y: batch
    dim3 block(448);     // 7 waves; wave w owns q = 28w..28w+27
    recon_kernel<<<grid, block, 0, stream>>>(
        (const float*)d_in[0], (const float*)d_in[1], (const float*)d_in[2],
        (const float*)d_in[3], (const float*)d_in[4], (const float*)d_in[5],
        (const float*)d_in[6], (const float*)d_in[7], (float*)d_out);
}